// Round 1
// baseline (2955.853 us; speedup 1.0000x reference)
//
#include <hip/hip_runtime.h>
#include <cstdint>

typedef unsigned short u16;
typedef __attribute__((ext_vector_type(4))) float f32x4;
typedef __attribute__((ext_vector_type(8))) __bf16 bf16x8;

typedef __attribute__((address_space(1))) void g_void;
typedef __attribute__((address_space(3))) void l_void;

__device__ __forceinline__ u16 f2bf(float f) {
  uint32_t u = __builtin_bit_cast(uint32_t, f);
  u += 0x7FFFu + ((u >> 16) & 1u);
  return (u16)(u >> 16);
}
__device__ __forceinline__ float bf2f(u16 h) {
  uint32_t u = ((uint32_t)h) << 16;
  return __builtin_bit_cast(float, u);
}

__device__ __forceinline__ void gload16(const void* g, void* l) {
  __builtin_amdgcn_global_load_lds((g_void*)g, (l_void*)l, 16, 0, 0);
}

// ---------------- weight transpose + bf16 convert: Wt[n][k] = W[k][n] ----------------
__global__ void transpose_w(const float* __restrict__ W, u16* __restrict__ Wt, int K, int N) {
  __shared__ float t[32][33];
  const int nb = blockIdx.x * 32, kb = blockIdx.y * 32;
  const int tx = threadIdx.x, ty = threadIdx.y;
#pragma unroll
  for (int i = 0; i < 32; i += 8)
    t[ty + i][tx] = W[(size_t)(kb + ty + i) * N + nb + tx];
  __syncthreads();
#pragma unroll
  for (int i = 0; i < 32; i += 8)
    Wt[(size_t)(nb + ty + i) * K + kb + tx] = f2bf(t[tx][ty + i]);
}

// ---------------- embedding ----------------
__global__ void embed_k(const int* __restrict__ z, const int* __restrict__ hgs,
                        const float* __restrict__ ae, const float* __restrict__ ne,
                        float* __restrict__ x, u16* __restrict__ xb) {
  const int row = blockIdx.x;
  const int b = row >> 7, tl = row & 127;
  int ia = 1, in_ = 0;
  if (tl > 0) { ia = z[b * 127 + tl - 1] + 2; in_ = hgs[b * 127 + tl - 1] + 2; }
  const float* ar = ae + (size_t)ia * 1024;
  const float* nr = ne + (size_t)in_ * 1024;
  for (int c = threadIdx.x; c < 1024; c += 256) {
    const float t = ar[c] + nr[c];
    x[(size_t)row * 1024 + c] = t;
    xb[(size_t)row * 1024 + c] = f2bf(t);
  }
}

// ---------------- distance bin index table (np.digitize semantics) ----------------
__global__ void didx_k(const float* __restrict__ pos, unsigned char* __restrict__ didx) {
  __shared__ float edges[85];
  const int bq = blockIdx.x;
  const int b = bq >> 7, lq = bq & 127;
  const int lk = threadIdx.x;
  if (threadIdx.x < 85) {
    const int k = threadIdx.x;
    double e = 0.75 + 0.05 * (double)k;
    float ef = (float)e;
    if (k == 0) ef = -1.0f; else if (k == 1) ef = 0.0f; else if (k == 2) ef = 0.01f;
    edges[k] = ef;
  }
  __syncthreads();
  unsigned char r;
  if (lq == 0 || lk == 0) {
    r = 1;  // cls row/col
  } else {
    const float* pi = pos + ((size_t)b * 127 + lq - 1) * 3;
    const float* pj = pos + ((size_t)b * 127 + lk - 1) * 3;
    const float dx = pi[0] - pj[0], dy = pi[1] - pj[1], dz = pi[2] - pj[2];
    const float d = sqrtf(dx * dx + dy * dy + dz * dz);
    int c = 0;
#pragma unroll
    for (int k2 = 0; k2 < 85; ++k2) c += (edges[k2] <= d) ? 1 : 0;
    r = (unsigned char)c;
  }
  didx[(size_t)b * 16384 + lq * 128 + lk] = r;
}

// ---------------- GEMM: C = A(MxK) * Bt(NxK)^T + bias, m97 structure ----------------
// MODE 0: qkv scatter -> Q(B,H,L,d) K(B,H,L,d) V(B,H,d,L)   MODE 1: plain bf16   MODE 2: gelu bf16
template <int MODE>
__launch_bounds__(256)
__global__ void gemm_bt(const u16* __restrict__ A, const u16* __restrict__ Bt,
                        const float* __restrict__ bias,
                        u16* __restrict__ O0, u16* __restrict__ O1, u16* __restrict__ O2,
                        int M, int N, int K) {
  __shared__ u16 As[128 * 32];
  __shared__ u16 Bs[128 * 32];
  const int tid = threadIdx.x;
  const int wv = tid >> 6;
  const int l = tid & 63;
  const int ntn = N >> 7;
  const int bm = blockIdx.x / ntn;
  const int bn = blockIdx.x % ntn;
  const int wr = (wv >> 1) * 64;
  const int wc = (wv & 1) * 64;

  const int srow = wv * 16 + (l >> 2);
  const int scol = (l & 3) * 8;
  const u16* Ag = A + (size_t)(bm * 128 + srow) * K + scol;
  const u16* Bg = Bt + (size_t)(bn * 128 + srow) * K + scol;
  u16* Als = &As[(wv * 16) * 32];
  u16* Bls = &Bs[(wv * 16) * 32];

  f32x4 acc[4][4];
#pragma unroll
  for (int m = 0; m < 4; ++m)
#pragma unroll
    for (int n = 0; n < 4; ++n) acc[m][n] = f32x4{0.f, 0.f, 0.f, 0.f};

  for (int k0 = 0; k0 < K; k0 += 32) {
    gload16(Ag + k0, Als);
    gload16(Ag + k0 + (size_t)64 * K, Als + 64 * 32);
    gload16(Bg + k0, Bls);
    gload16(Bg + k0 + (size_t)64 * K, Bls + 64 * 32);
    __syncthreads();
    const int fr = l & 15;
    const int fk = (l >> 4) * 8;
    bf16x8 af[4], bfr[4];
#pragma unroll
    for (int m = 0; m < 4; ++m)
      af[m] = *(const bf16x8*)&As[(wr + m * 16 + fr) * 32 + fk];
#pragma unroll
    for (int n = 0; n < 4; ++n)
      bfr[n] = *(const bf16x8*)&Bs[(wc + n * 16 + fr) * 32 + fk];
#pragma unroll
    for (int m = 0; m < 4; ++m)
#pragma unroll
      for (int n = 0; n < 4; ++n)
        acc[m][n] = __builtin_amdgcn_mfma_f32_16x16x32_bf16(af[m], bfr[n], acc[m][n], 0, 0, 0);
    __syncthreads();
  }

  const int fr = l & 15;
  const int fq = l >> 4;
  const int colbase = bn * 128 + wc;
  const int rowbase = bm * 128 + wr;
  float bv[4];
#pragma unroll
  for (int n = 0; n < 4; ++n) bv[n] = bias[colbase + n * 16 + fr];

#pragma unroll
  for (int m = 0; m < 4; ++m) {
    const int row0 = rowbase + m * 16 + fq * 4;
#pragma unroll
    for (int n = 0; n < 4; ++n) {
      const int col = colbase + n * 16 + fr;
#pragma unroll
      for (int j = 0; j < 4; ++j) {
        float v = acc[m][n][j] + bv[n];
        const int row = row0 + j;
        if (MODE == 2) v = 0.5f * v * (1.f + erff(v * 0.7071067811865475f));
        if (MODE == 0) {
          const int bI = row >> 7, tl = row & 127;
          if (col < 1024) {
            const int h = col >> 6, d = col & 63;
            O0[(((size_t)bI * 16 + h) * 128 + tl) * 64 + d] = f2bf(v);
          } else if (col < 2048) {
            const int c = col - 1024, h = c >> 6, d = c & 63;
            O1[(((size_t)bI * 16 + h) * 128 + tl) * 64 + d] = f2bf(v);
          } else {
            const int c = col - 2048, h = c >> 6, d = c & 63;
            O2[(((size_t)bI * 16 + h) * 64 + d) * 128 + tl] = f2bf(v);
          }
        } else {
          O0[(size_t)row * N + col] = f2bf(v);
        }
      }
    }
  }
}

// ---------------- fused attention: one block per (b,h) ----------------
__launch_bounds__(256)
__global__ void attn_kernel(const u16* __restrict__ Qg, const u16* __restrict__ Kg,
                            const u16* __restrict__ Vg,
                            const unsigned char* __restrict__ didx,
                            const float* __restrict__ demb_g,
                            u16* __restrict__ Og) {
  __shared__ u16 QK[2 * 128 * 64];  // Q | K, later reused as P (4 waves x 32x128)
  __shared__ u16 Vt[64 * 128];      // V transposed (d, keys)
  __shared__ float dh[86];          // dist_emb column for this head
  const int tid = threadIdx.x;
  const int wv = tid >> 6;
  const int l = tid & 63;
  const int bh = blockIdx.x;
  const int b = bh >> 4, h = bh & 15;

  for (int i = tid; i < 86; i += 256) dh[i] = demb_g[i * 16 + h];

  const char* Qs = (const char*)(Qg + (size_t)bh * 8192);
  const char* Ks = (const char*)(Kg + (size_t)bh * 8192);
  const char* Vs = (const char*)(Vg + (size_t)bh * 8192);
  char* QKb = (char*)QK;
  char* Vtb = (char*)Vt;
#pragma unroll
  for (int it = 0; it < 4; ++it) {
    const int r = it * 32 + (tid >> 3);
    const int cb = (tid & 7) * 16;
    const int sw = cb ^ ((r & 7) << 4);
    *(uint4*)(QKb + r * 128 + sw) = *(const uint4*)(Qs + r * 128 + cb);
    *(uint4*)(QKb + 16384 + r * 128 + sw) = *(const uint4*)(Ks + r * 128 + cb);
  }
#pragma unroll
  for (int it = 0; it < 4; ++it) {
    const int r = it * 16 + (tid >> 4);
    const int cb = (tid & 15) * 16;
    const int sw = cb ^ ((r & 7) << 4);
    *(uint4*)(Vtb + r * 256 + sw) = *(const uint4*)(Vs + r * 256 + cb);
  }
  __syncthreads();

  // S = Q K^T for rows [wv*32, wv*32+32)
  f32x4 s[2][8];
#pragma unroll
  for (int m = 0; m < 2; ++m)
#pragma unroll
    for (int n = 0; n < 8; ++n) s[m][n] = f32x4{0.f, 0.f, 0.f, 0.f};
#pragma unroll
  for (int kk = 0; kk < 2; ++kk) {
    bf16x8 qa[2], kb[8];
#pragma unroll
    for (int m = 0; m < 2; ++m) {
      const int qr = wv * 32 + m * 16 + (l & 15);
      qa[m] = *(const bf16x8*)(QKb + qr * 128 + ((kk * 64 + (l >> 4) * 16) ^ ((qr & 7) << 4)));
    }
#pragma unroll
    for (int n = 0; n < 8; ++n) {
      const int kr = n * 16 + (l & 15);
      kb[n] = *(const bf16x8*)(QKb + 16384 + kr * 128 + ((kk * 64 + (l >> 4) * 16) ^ ((kr & 7) << 4)));
    }
#pragma unroll
    for (int m = 0; m < 2; ++m)
#pragma unroll
      for (int n = 0; n < 8; ++n)
        s[m][n] = __builtin_amdgcn_mfma_f32_16x16x32_bf16(qa[m], kb[n], s[m][n], 0, 0, 0);
  }

  // mask + softmax (rows distributed: row = wv*32 + m*16 + (l>>4)*4 + j, cols n*16+(l&15))
  const unsigned char* dd = didx + (size_t)b * 16384;
  float rinv[2][4];
#pragma unroll
  for (int m = 0; m < 2; ++m) {
#pragma unroll
    for (int j = 0; j < 4; ++j) {
      const int lq = wv * 32 + m * 16 + (l >> 4) * 4 + j;
      const unsigned char* drow = dd + lq * 128;
      float vals[8];
#pragma unroll
      for (int n = 0; n < 8; ++n) {
        const int lk = n * 16 + (l & 15);
        vals[n] = s[m][n][j] * 0.125f + dh[drow[lk]];
      }
      float mx = vals[0];
#pragma unroll
      for (int n = 1; n < 8; ++n) mx = fmaxf(mx, vals[n]);
#pragma unroll
      for (int o = 1; o < 16; o <<= 1) mx = fmaxf(mx, __shfl_xor(mx, o, 64));
      float sum = 0.f;
#pragma unroll
      for (int n = 0; n < 8; ++n) { vals[n] = expf(vals[n] - mx); sum += vals[n]; }
#pragma unroll
      for (int o = 1; o < 16; o <<= 1) sum += __shfl_xor(sum, o, 64);
      rinv[m][j] = 1.f / sum;
#pragma unroll
      for (int n = 0; n < 8; ++n) s[m][n][j] = vals[n];
    }
  }
  __syncthreads();  // all waves done reading Q/K LDS
  // write P (unnormalized, bf16) into reused QK region: per-wave 32x128
  char* Pb = QKb + wv * 8192;
#pragma unroll
  for (int m = 0; m < 2; ++m)
#pragma unroll
    for (int n = 0; n < 8; ++n)
#pragma unroll
      for (int j = 0; j < 4; ++j) {
        const int pr = m * 16 + (l >> 4) * 4 + j;
        const int pc = (n * 16 + (l & 15)) * 2;
        *(u16*)(Pb + pr * 256 + (pc ^ ((pr & 7) << 4))) = f2bf(s[m][n][j]);
      }
  __syncthreads();

  // O = P V : rows 32, cols 64, K = 128 keys
  f32x4 o_[2][4];
#pragma unroll
  for (int m = 0; m < 2; ++m)
#pragma unroll
    for (int n = 0; n < 4; ++n) o_[m][n] = f32x4{0.f, 0.f, 0.f, 0.f};
#pragma unroll
  for (int ks = 0; ks < 4; ++ks) {
    bf16x8 pa[2], vb[4];
#pragma unroll
    for (int m = 0; m < 2; ++m) {
      const int pr = m * 16 + (l & 15);
      pa[m] = *(const bf16x8*)(Pb + pr * 256 + ((ks * 64 + (l >> 4) * 16) ^ ((pr & 7) << 4)));
    }
#pragma unroll
    for (int n = 0; n < 4; ++n) {
      const int vr = n * 16 + (l & 15);
      vb[n] = *(const bf16x8*)(Vtb + vr * 256 + ((ks * 64 + (l >> 4) * 16) ^ ((vr & 7) << 4)));
    }
#pragma unroll
    for (int m = 0; m < 2; ++m)
#pragma unroll
      for (int n = 0; n < 4; ++n)
        o_[m][n] = __builtin_amdgcn_mfma_f32_16x16x32_bf16(pa[m], vb[n], o_[m][n], 0, 0, 0);
  }
#pragma unroll
  for (int m = 0; m < 2; ++m)
#pragma unroll
    for (int n = 0; n < 4; ++n)
#pragma unroll
      for (int j = 0; j < 4; ++j) {
        const int lo = wv * 32 + m * 16 + (l >> 4) * 4 + j;
        const int d = n * 16 + (l & 15);
        Og[((size_t)b * 128 + lo) * 1024 + h * 64 + d] = f2bf(o_[m][n][j] * rinv[m][j]);
      }
}

// ---------------- residual + LayerNorm ----------------
__launch_bounds__(256)
__global__ void ln_res(float* __restrict__ x, const u16* __restrict__ o,
                       const float* __restrict__ gam, const float* __restrict__ bet,
                       u16* __restrict__ xb) {
  const int row = blockIdx.x * 4 + (threadIdx.x >> 6);
  const int l = threadIdx.x & 63;
  const size_t base = (size_t)row * 1024;
  float v[16];
  float s = 0.f, sq = 0.f;
#pragma unroll
  for (int i = 0; i < 16; ++i) {
    const int c = i * 64 + l;
    const float t = x[base + c] + bf2f(o[base + c]);
    v[i] = t; s += t; sq += t * t;
  }
#pragma unroll
  for (int off = 1; off < 64; off <<= 1) {
    s += __shfl_xor(s, off, 64);
    sq += __shfl_xor(sq, off, 64);
  }
  const float mean = s * (1.f / 1024.f);
  const float var = sq * (1.f / 1024.f) - mean * mean;
  const float rstd = rsqrtf(var + 1e-5f);
#pragma unroll
  for (int i = 0; i < 16; ++i) {
    const int c = i * 64 + l;
    const float y = (v[i] - mean) * rstd * gam[c] + bet[c];
    x[base + c] = y;
    xb[base + c] = f2bf(y);
  }
}

// ---------------- extract cls rows ----------------
__global__ void extract_cls(const float* __restrict__ x, float* __restrict__ out) {
  const int b = blockIdx.x;
  for (int c = threadIdx.x; c < 1024; c += 256)
    out[(size_t)b * 1024 + c] = x[(size_t)b * 131072 + c];
}

extern "C" void kernel_launch(void* const* d_in, const int* in_sizes, int n_in,
                              void* d_out, int out_size, void* d_ws, size_t ws_size,
                              hipStream_t stream) {
  const int* z = (const int*)d_in[0];
  const int* hgs = (const int*)d_in[1];
  const float* pos = (const float*)d_in[2];
  // d_in[3] = batch (int64), unused (uniform graphs)
  const float* atoms_emb = (const float*)d_in[4];
  const float* neigh_emb = (const float*)d_in[5];
  const float* dist_emb = (const float*)d_in[6];
  const float* Wqkv = (const float*)d_in[7];
  const float* bqkv = (const float*)d_in[8];
  const float* Wo = (const float*)d_in[9];
  const float* bo = (const float*)d_in[10];
  const float* W1 = (const float*)d_in[11];
  const float* b1f = (const float*)d_in[12];
  const float* W2 = (const float*)d_in[13];
  const float* b2f = (const float*)d_in[14];
  const float* ln1g = (const float*)d_in[15];
  const float* ln1b = (const float*)d_in[16];
  const float* ln2g = (const float*)d_in[17];
  const float* ln2b = (const float*)d_in[18];

  size_t off = 0;
  char* wsb = (char*)d_ws;
  auto alc = [&](size_t bytes) { void* p = wsb + off; off += (bytes + 255) & ~(size_t)255; return p; };
  float* xf = (float*)alc(8192ull * 1024 * 4);
  u16* xb = (u16*)alc(8192ull * 1024 * 2);
  u16* q = (u16*)alc(8192ull * 1024 * 2);
  u16* k = (u16*)alc(8192ull * 1024 * 2);
  u16* v = (u16*)alc(8192ull * 1024 * 2);
  u16* big = (u16*)alc(8192ull * 3072 * 2);   // attn_out (first 1/3) and FF hidden
  u16* proj = (u16*)alc(8192ull * 1024 * 2);
  u16* wqkvt = (u16*)alc(3072ull * 1024 * 2);
  u16* wot = (u16*)alc(1024ull * 1024 * 2);
  u16* w1t = (u16*)alc(3072ull * 1024 * 2);
  u16* w2t = (u16*)alc(1024ull * 3072 * 2);
  unsigned char* didx = (unsigned char*)alc(64ull * 128 * 128);

  transpose_w<<<dim3(96, 32), dim3(32, 8), 0, stream>>>(Wqkv, wqkvt, 1024, 3072);
  transpose_w<<<dim3(32, 32), dim3(32, 8), 0, stream>>>(Wo, wot, 1024, 1024);
  transpose_w<<<dim3(96, 32), dim3(32, 8), 0, stream>>>(W1, w1t, 1024, 3072);
  transpose_w<<<dim3(32, 96), dim3(32, 8), 0, stream>>>(W2, w2t, 3072, 1024);
  embed_k<<<8192, 256, 0, stream>>>(z, hgs, atoms_emb, neigh_emb, xf, xb);
  didx_k<<<8192, 128, 0, stream>>>(pos, didx);

  for (int layer = 0; layer < 8; ++layer) {
    gemm_bt<0><<<1536, 256, 0, stream>>>(xb, wqkvt, bqkv, q, k, v, 8192, 3072, 1024);
    attn_kernel<<<1024, 256, 0, stream>>>(q, k, v, didx, dist_emb, big);
    gemm_bt<1><<<512, 256, 0, stream>>>(big, wot, bo, proj, nullptr, nullptr, 8192, 1024, 1024);
    ln_res<<<2048, 256, 0, stream>>>(xf, proj, ln1g, ln1b, xb);
    gemm_bt<2><<<1536, 256, 0, stream>>>(xb, w1t, b1f, big, nullptr, nullptr, 8192, 3072, 1024);
    gemm_bt<1><<<512, 256, 0, stream>>>(big, w2t, b2f, proj, nullptr, nullptr, 8192, 1024, 3072);
    ln_res<<<2048, 256, 0, stream>>>(xf, proj, ln2g, ln2b, xb);
  }
  extract_cls<<<64, 256, 0, stream>>>(xf, (float*)d_out);
}

// Round 2
// 2801.656 us; speedup vs baseline: 1.0550x; 1.0550x over previous
//
#include <hip/hip_runtime.h>
#include <cstdint>

typedef unsigned short u16;
typedef __attribute__((ext_vector_type(4))) float f32x4;
typedef __attribute__((ext_vector_type(8))) __bf16 bf16x8;

typedef __attribute__((address_space(1))) void g_void;
typedef __attribute__((address_space(3))) void l_void;

__device__ __forceinline__ u16 f2bf(float f) {
  uint32_t u = __builtin_bit_cast(uint32_t, f);
  u += 0x7FFFu + ((u >> 16) & 1u);
  return (u16)(u >> 16);
}
__device__ __forceinline__ float bf2f(u16 h) {
  uint32_t u = ((uint32_t)h) << 16;
  return __builtin_bit_cast(float, u);
}

__device__ __forceinline__ void gload16(const void* g, void* l) {
  __builtin_amdgcn_global_load_lds((g_void*)g, (l_void*)l, 16, 0, 0);
}

// branchless exact-enough GELU: erf via A&S 7.1.26 (max abs err 1.5e-7)
__device__ __forceinline__ float gelu_exact(float x) {
  float a = x * 0.70710678118654752f;
  float s = fabsf(a);
  float t = __builtin_amdgcn_rcpf(fmaf(0.3275911f, s, 1.0f));
  float p = fmaf(fmaf(fmaf(fmaf(1.061405429f, t, -1.453152027f), t, 1.421413741f), t,
                      -0.284496736f), t, 0.254829592f);
  p *= t;
  float e = __expf(-s * s);
  float er = fmaf(-p, e, 1.0f);
  er = copysignf(er, a);
  return 0.5f * x * (1.0f + er);
}

// ---------------- weight transpose + bf16 convert: Wt[n][k] = W[k][n] ----------------
__global__ void transpose_w(const float* __restrict__ W, u16* __restrict__ Wt, int K, int N) {
  __shared__ float t[32][33];
  const int nb = blockIdx.x * 32, kb = blockIdx.y * 32;
  const int tx = threadIdx.x, ty = threadIdx.y;
#pragma unroll
  for (int i = 0; i < 32; i += 8)
    t[ty + i][tx] = W[(size_t)(kb + ty + i) * N + nb + tx];
  __syncthreads();
#pragma unroll
  for (int i = 0; i < 32; i += 8)
    Wt[(size_t)(nb + ty + i) * K + kb + tx] = f2bf(t[tx][ty + i]);
}

// ---------------- embedding ----------------
__global__ void embed_k(const int* __restrict__ z, const int* __restrict__ hgs,
                        const float* __restrict__ ae, const float* __restrict__ ne,
                        float* __restrict__ x, u16* __restrict__ xb) {
  const int row = blockIdx.x;
  const int b = row >> 7, tl = row & 127;
  int ia = 1, in_ = 0;
  if (tl > 0) { ia = z[b * 127 + tl - 1] + 2; in_ = hgs[b * 127 + tl - 1] + 2; }
  const float* ar = ae + (size_t)ia * 1024;
  const float* nr = ne + (size_t)in_ * 1024;
  for (int c = threadIdx.x; c < 1024; c += 256) {
    const float t = ar[c] + nr[c];
    x[(size_t)row * 1024 + c] = t;
    xb[(size_t)row * 1024 + c] = f2bf(t);
  }
}

// ---------------- distance bin index table (np.digitize semantics) ----------------
__global__ void didx_k(const float* __restrict__ pos, unsigned char* __restrict__ didx) {
  __shared__ float edges[85];
  const int bq = blockIdx.x;
  const int b = bq >> 7, lq = bq & 127;
  const int lk = threadIdx.x;
  if (threadIdx.x < 85) {
    const int k = threadIdx.x;
    double e = 0.75 + 0.05 * (double)k;
    float ef = (float)e;
    if (k == 0) ef = -1.0f; else if (k == 1) ef = 0.0f; else if (k == 2) ef = 0.01f;
    edges[k] = ef;
  }
  __syncthreads();
  unsigned char r;
  if (lq == 0 || lk == 0) {
    r = 1;  // cls row/col
  } else {
    const float* pi = pos + ((size_t)b * 127 + lq - 1) * 3;
    const float* pj = pos + ((size_t)b * 127 + lk - 1) * 3;
    const float dx = pi[0] - pj[0], dy = pi[1] - pj[1], dz = pi[2] - pj[2];
    const float d = sqrtf(dx * dx + dy * dy + dz * dz);
    int c = 0;
#pragma unroll
    for (int k2 = 0; k2 < 85; ++k2) c += (edges[k2] <= d) ? 1 : 0;
    r = (unsigned char)c;
  }
  didx[(size_t)b * 16384 + lq * 128 + lk] = r;
}

// ---------------- 256x256 8-phase GEMM: C = A(8192xK) * Bt(NxK)^T + bias ----------------
// MODE 0: qkv scatter -> Q(B,H,L,d) K(B,H,L,d) V(B,H,d,L)   MODE 1: plain bf16   MODE 2: gelu bf16
// LDS: 2 buf x 2 op(A,B) x 2 kh x 16KB slab (slab = 256 rows x 32 cols bf16, st_16x32 swizzled)
template <int MODE>
__launch_bounds__(512, 2)
__global__ void gemm8(const u16* __restrict__ A, const u16* __restrict__ Bt,
                      const float* __restrict__ bias,
                      u16* __restrict__ O0, u16* __restrict__ O1, u16* __restrict__ O2,
                      int N, int K) {
  extern __shared__ char lds[];
  const int tid = threadIdx.x;
  const int w = tid >> 6, l = tid & 63;
  const int wr = w >> 2, wc = w & 3;
  // bijective XCD swizzle (gridDim % 8 == 0 for all our shapes)
  const int nwg = gridDim.x;
  const int wg = (blockIdx.x & 7) * (nwg >> 3) + (blockIdx.x >> 3);
  const int ntn = N >> 8;
  const int bm = wg / ntn, bn = wg % ntn;
  const int NT = K >> 6;

  // staging chunk -> (row, col) under st_16x32 layout (inverse swizzle on global source)
  const int r15 = l >> 2;
  const int row0 = w * 16 + r15;          // chunk j=0
  const int row1 = row0 + 128;            // chunk j=1
  const int colc = ((((l & 3) << 4) ^ (((r15 >> 3) & 1) << 5)) >> 1);
  const size_t aoff0 = (size_t)(bm * 256 + row0) * K + colc;
  const size_t aoff1 = (size_t)(bm * 256 + row1) * K + colc;
  const size_t boff0 = (size_t)(bn * 256 + row0) * K + colc;
  const size_t boff1 = (size_t)(bn * 256 + row1) * K + colc;
  const int ldsw = w << 10;

  // fragment read lane offset (swizzled)
  const int lo = ((l & 15) << 6) + (((l >> 4) << 4) ^ ((l & 8) << 2));

  auto stA = [&](int ts, int par, int kh) {
    const int kb = ts * 64 + kh * 32;
    char* slab = lds + (((((par << 1) | 0) << 1) | kh) << 14);
    gload16(A + aoff0 + kb, slab + ldsw);
    gload16(A + aoff1 + kb, slab + 8192 + ldsw);
  };
  auto stB = [&](int ts, int par, int kh) {
    const int kb = ts * 64 + kh * 32;
    char* slab = lds + (((((par << 1) | 1) << 1) | kh) << 14);
    gload16(Bt + boff0 + kb, slab + ldsw);
    gload16(Bt + boff1 + kb, slab + 8192 + ldsw);
  };
  auto ldA = [&](int par, int kk, int mh, bf16x8* af) {
    const char* slab = lds + (((((par << 1) | 0) << 1) | kk) << 14) + (wr << 13) + (mh << 12);
#pragma unroll
    for (int i = 0; i < 4; ++i) af[i] = *(const bf16x8*)(slab + (i << 10) + lo);
  };
  auto ldB = [&](int par, int kk, bf16x8* bf) {
    const char* slab = lds + (((((par << 1) | 1) << 1) | kk) << 14) + (wc << 12);
#pragma unroll
    for (int i = 0; i < 4; ++i) bf[i] = *(const bf16x8*)(slab + (i << 10) + lo);
  };

  f32x4 acc[8][4];
#pragma unroll
  for (int m = 0; m < 8; ++m)
#pragma unroll
    for (int n = 0; n < 4; ++n) acc[m][n] = f32x4{0.f, 0.f, 0.f, 0.f};

  auto MM = [&](int mh, bf16x8* af, bf16x8* bf) {
#pragma unroll
    for (int i = 0; i < 4; ++i)
#pragma unroll
      for (int n = 0; n < 4; ++n)
        acc[mh * 4 + i][n] =
            __builtin_amdgcn_mfma_f32_16x16x32_bf16(af[i], bf[n], acc[mh * 4 + i][n], 0, 0, 0);
  };

  // prologue: tile0 fully + tile1 kh0
  stA(0, 0, 0); stB(0, 0, 0); stA(0, 0, 1); stB(0, 0, 1); stA(1, 1, 0); stB(1, 1, 0);
  asm volatile("s_waitcnt vmcnt(4)" ::: "memory");
  __builtin_amdgcn_s_barrier();

  for (int t = 0; t < NT; ++t) {
    const int par = t & 1;
    const int par1 = par ^ 1;
    const int t1 = (t + 1 < NT) ? t + 1 : NT - 1;
    const int t2 = (t + 2 < NT) ? t + 2 : NT - 1;
    bf16x8 af[4], bf[4];
    // ---- phase 0: kk0, frag-half 0; stage A(t+1, kh1) ----
    ldA(par, 0, 0, af); ldB(par, 0, bf);
    stA(t1, par1, 1);
    __builtin_amdgcn_s_barrier();
    __builtin_amdgcn_s_setprio(1); MM(0, af, bf); __builtin_amdgcn_s_setprio(0);
    __builtin_amdgcn_s_barrier();
    // ---- phase 1: kk0, frag-half 1; stage B(t+1, kh1) ----
    ldA(par, 0, 1, af);
    stB(t1, par1, 1);
    __builtin_amdgcn_s_barrier();
    __builtin_amdgcn_s_setprio(1); MM(1, af, bf); __builtin_amdgcn_s_setprio(0);
    asm volatile("s_waitcnt vmcnt(4)" ::: "memory");
    __builtin_amdgcn_s_barrier();
    // ---- phase 2: kk1, frag-half 0; stage A(t+2, kh0) (recycles current buf kh0) ----
    ldA(par, 1, 0, af); ldB(par, 1, bf);
    stA(t2, par, 0);
    __builtin_amdgcn_s_barrier();
    __builtin_amdgcn_s_setprio(1); MM(0, af, bf); __builtin_amdgcn_s_setprio(0);
    __builtin_amdgcn_s_barrier();
    // ---- phase 3: kk1, frag-half 1; stage B(t+2, kh0) ----
    ldA(par, 1, 1, af);
    stB(t2, par, 0);
    __builtin_amdgcn_s_barrier();
    __builtin_amdgcn_s_setprio(1); MM(1, af, bf); __builtin_amdgcn_s_setprio(0);
    asm volatile("s_waitcnt vmcnt(4)" ::: "memory");
    __builtin_amdgcn_s_barrier();
  }
  asm volatile("s_waitcnt vmcnt(0)" ::: "memory");

  // epilogue
  const int fr = l & 15, fq = l >> 4;
  const int colb = bn * 256 + wc * 64;
  const int rowb = bm * 256 + wr * 128;
  float bv[4];
#pragma unroll
  for (int n = 0; n < 4; ++n) bv[n] = bias[colb + n * 16 + fr];
  const int region = colb >> 10;
#pragma unroll
  for (int m = 0; m < 8; ++m) {
#pragma unroll
    for (int n = 0; n < 4; ++n) {
      const int col = colb + n * 16 + fr;
#pragma unroll
      for (int j = 0; j < 4; ++j) {
        const int row = rowb + m * 16 + fq * 4 + j;
        float v = acc[m][n][j] + bv[n];
        if (MODE == 2) v = gelu_exact(v);
        if (MODE == 0) {
          const int bI = row >> 7, tl = row & 127;
          const int c = col - (region << 10);
          const int h = c >> 6, d = c & 63;
          if (region == 0)      O0[(((size_t)bI * 16 + h) * 128 + tl) * 64 + d] = f2bf(v);
          else if (region == 1) O1[(((size_t)bI * 16 + h) * 128 + tl) * 64 + d] = f2bf(v);
          else                  O2[(((size_t)bI * 16 + h) * 64 + d) * 128 + tl] = f2bf(v);
        } else {
          O0[(size_t)row * N + col] = f2bf(v);
        }
      }
    }
  }
}

// ---------------- fused attention: one block per (b,h) ----------------
__launch_bounds__(256)
__global__ void attn_kernel(const u16* __restrict__ Qg, const u16* __restrict__ Kg,
                            const u16* __restrict__ Vg,
                            const unsigned char* __restrict__ didx,
                            const float* __restrict__ demb_g,
                            u16* __restrict__ Og) {
  __shared__ u16 QK[2 * 128 * 64];  // Q | K, later reused as P (4 waves x 32x128)
  __shared__ u16 Vt[64 * 128];      // V transposed (d, keys)
  __shared__ float dh[86];          // dist_emb column for this head
  const int tid = threadIdx.x;
  const int wv = tid >> 6;
  const int l = tid & 63;
  const int bh = blockIdx.x;
  const int b = bh >> 4, h = bh & 15;

  for (int i = tid; i < 86; i += 256) dh[i] = demb_g[i * 16 + h];

  const char* Qs = (const char*)(Qg + (size_t)bh * 8192);
  const char* Ks = (const char*)(Kg + (size_t)bh * 8192);
  const char* Vs = (const char*)(Vg + (size_t)bh * 8192);
  char* QKb = (char*)QK;
  char* Vtb = (char*)Vt;
#pragma unroll
  for (int it = 0; it < 4; ++it) {
    const int r = it * 32 + (tid >> 3);
    const int cb = (tid & 7) * 16;
    const int sw = cb ^ ((r & 7) << 4);
    *(uint4*)(QKb + r * 128 + sw) = *(const uint4*)(Qs + r * 128 + cb);
    *(uint4*)(QKb + 16384 + r * 128 + sw) = *(const uint4*)(Ks + r * 128 + cb);
  }
#pragma unroll
  for (int it = 0; it < 4; ++it) {
    const int r = it * 16 + (tid >> 4);
    const int cb = (tid & 15) * 16;
    const int sw = cb ^ ((r & 7) << 4);
    *(uint4*)(Vtb + r * 256 + sw) = *(const uint4*)(Vs + r * 256 + cb);
  }
  __syncthreads();

  // S = Q K^T for rows [wv*32, wv*32+32)
  f32x4 s[2][8];
#pragma unroll
  for (int m = 0; m < 2; ++m)
#pragma unroll
    for (int n = 0; n < 8; ++n) s[m][n] = f32x4{0.f, 0.f, 0.f, 0.f};
#pragma unroll
  for (int kk = 0; kk < 2; ++kk) {
    bf16x8 qa[2], kb[8];
#pragma unroll
    for (int m = 0; m < 2; ++m) {
      const int qr = wv * 32 + m * 16 + (l & 15);
      qa[m] = *(const bf16x8*)(QKb + qr * 128 + ((kk * 64 + (l >> 4) * 16) ^ ((qr & 7) << 4)));
    }
#pragma unroll
    for (int n = 0; n < 8; ++n) {
      const int kr = n * 16 + (l & 15);
      kb[n] = *(const bf16x8*)(QKb + 16384 + kr * 128 + ((kk * 64 + (l >> 4) * 16) ^ ((kr & 7) << 4)));
    }
#pragma unroll
    for (int m = 0; m < 2; ++m)
#pragma unroll
      for (int n = 0; n < 8; ++n)
        s[m][n] = __builtin_amdgcn_mfma_f32_16x16x32_bf16(qa[m], kb[n], s[m][n], 0, 0, 0);
  }

  const unsigned char* dd = didx + (size_t)b * 16384;
  float rinv[2][4];
#pragma unroll
  for (int m = 0; m < 2; ++m) {
#pragma unroll
    for (int j = 0; j < 4; ++j) {
      const int lq = wv * 32 + m * 16 + (l >> 4) * 4 + j;
      const unsigned char* drow = dd + lq * 128;
      float vals[8];
#pragma unroll
      for (int n = 0; n < 8; ++n) {
        const int lk = n * 16 + (l & 15);
        vals[n] = s[m][n][j] * 0.125f + dh[drow[lk]];
      }
      float mx = vals[0];
#pragma unroll
      for (int n = 1; n < 8; ++n) mx = fmaxf(mx, vals[n]);
#pragma unroll
      for (int o = 1; o < 16; o <<= 1) mx = fmaxf(mx, __shfl_xor(mx, o, 64));
      float sum = 0.f;
#pragma unroll
      for (int n = 0; n < 8; ++n) { vals[n] = expf(vals[n] - mx); sum += vals[n]; }
#pragma unroll
      for (int o = 1; o < 16; o <<= 1) sum += __shfl_xor(sum, o, 64);
      rinv[m][j] = 1.f / sum;
#pragma unroll
      for (int n = 0; n < 8; ++n) s[m][n][j] = vals[n];
    }
  }
  __syncthreads();
  char* Pb = QKb + wv * 8192;
#pragma unroll
  for (int m = 0; m < 2; ++m)
#pragma unroll
    for (int n = 0; n < 8; ++n)
#pragma unroll
      for (int j = 0; j < 4; ++j) {
        const int pr = m * 16 + (l >> 4) * 4 + j;
        const int pc = (n * 16 + (l & 15)) * 2;
        *(u16*)(Pb + pr * 256 + (pc ^ ((pr & 7) << 4))) = f2bf(s[m][n][j]);
      }
  __syncthreads();

  f32x4 o_[2][4];
#pragma unroll
  for (int m = 0; m < 2; ++m)
#pragma unroll
    for (int n = 0; n < 4; ++n) o_[m][n] = f32x4{0.f, 0.f, 0.f, 0.f};
#pragma unroll
  for (int ks = 0; ks < 4; ++ks) {
    bf16x8 pa[2], vb[4];
#pragma unroll
    for (int m = 0; m < 2; ++m) {
      const int pr = m * 16 + (l & 15);
      pa[m] = *(const bf16x8*)(Pb + pr * 256 + ((ks * 64 + (l >> 4) * 16) ^ ((pr & 7) << 4)));
    }
#pragma unroll
    for (int n = 0; n < 4; ++n) {
      const int vr = n * 16 + (l & 15);
      vb[n] = *(const bf16x8*)(Vtb + vr * 256 + ((ks * 64 + (l >> 4) * 16) ^ ((vr & 7) << 4)));
    }
#pragma unroll
    for (int m = 0; m < 2; ++m)
#pragma unroll
      for (int n = 0; n < 4; ++n)
        o_[m][n] = __builtin_amdgcn_mfma_f32_16x16x32_bf16(pa[m], vb[n], o_[m][n], 0, 0, 0);
  }
#pragma unroll
  for (int m = 0; m < 2; ++m)
#pragma unroll
    for (int n = 0; n < 4; ++n)
#pragma unroll
      for (int j = 0; j < 4; ++j) {
        const int lo2 = wv * 32 + m * 16 + (l >> 4) * 4 + j;
        const int d = n * 16 + (l & 15);
        Og[((size_t)b * 128 + lo2) * 1024 + h * 64 + d] = f2bf(o_[m][n][j] * rinv[m][j]);
      }
}

// ---------------- residual + LayerNorm ----------------
__launch_bounds__(256)
__global__ void ln_res(float* __restrict__ x, const u16* __restrict__ o,
                       const float* __restrict__ gam, const float* __restrict__ bet,
                       u16* __restrict__ xb) {
  const int row = blockIdx.x * 4 + (threadIdx.x >> 6);
  const int l = threadIdx.x & 63;
  const size_t base = (size_t)row * 1024;
  float v[16];
  float s = 0.f, sq = 0.f;
#pragma unroll
  for (int i = 0; i < 16; ++i) {
    const int c = i * 64 + l;
    const float t = x[base + c] + bf2f(o[base + c]);
    v[i] = t; s += t; sq += t * t;
  }
#pragma unroll
  for (int off = 1; off < 64; off <<= 1) {
    s += __shfl_xor(s, off, 64);
    sq += __shfl_xor(sq, off, 64);
  }
  const float mean = s * (1.f / 1024.f);
  const float var = sq * (1.f / 1024.f) - mean * mean;
  const float rstd = rsqrtf(var + 1e-5f);
#pragma unroll
  for (int i = 0; i < 16; ++i) {
    const int c = i * 64 + l;
    const float y = (v[i] - mean) * rstd * gam[c] + bet[c];
    x[base + c] = y;
    xb[base + c] = f2bf(y);
  }
}

// ---------------- extract cls rows ----------------
__global__ void extract_cls(const float* __restrict__ x, float* __restrict__ out) {
  const int b = blockIdx.x;
  for (int c = threadIdx.x; c < 1024; c += 256)
    out[(size_t)b * 1024 + c] = x[(size_t)b * 131072 + c];
}

extern "C" void kernel_launch(void* const* d_in, const int* in_sizes, int n_in,
                              void* d_out, int out_size, void* d_ws, size_t ws_size,
                              hipStream_t stream) {
  const int* z = (const int*)d_in[0];
  const int* hgs = (const int*)d_in[1];
  const float* pos = (const float*)d_in[2];
  const float* atoms_emb = (const float*)d_in[4];
  const float* neigh_emb = (const float*)d_in[5];
  const float* dist_emb = (const float*)d_in[6];
  const float* Wqkv = (const float*)d_in[7];
  const float* bqkv = (const float*)d_in[8];
  const float* Wo = (const float*)d_in[9];
  const float* bo = (const float*)d_in[10];
  const float* W1 = (const float*)d_in[11];
  const float* b1f = (const float*)d_in[12];
  const float* W2 = (const float*)d_in[13];
  const float* b2f = (const float*)d_in[14];
  const float* ln1g = (const float*)d_in[15];
  const float* ln1b = (const float*)d_in[16];
  const float* ln2g = (const float*)d_in[17];
  const float* ln2b = (const float*)d_in[18];

  size_t off = 0;
  char* wsb = (char*)d_ws;
  auto alc = [&](size_t bytes) { void* p = wsb + off; off += (bytes + 255) & ~(size_t)255; return p; };
  float* xf = (float*)alc(8192ull * 1024 * 4);
  u16* xb = (u16*)alc(8192ull * 1024 * 2);
  u16* q = (u16*)alc(8192ull * 1024 * 2);
  u16* k = (u16*)alc(8192ull * 1024 * 2);
  u16* v = (u16*)alc(8192ull * 1024 * 2);
  u16* big = (u16*)alc(8192ull * 3072 * 2);
  u16* proj = (u16*)alc(8192ull * 1024 * 2);
  u16* wqkvt = (u16*)alc(3072ull * 1024 * 2);
  u16* wot = (u16*)alc(1024ull * 1024 * 2);
  u16* w1t = (u16*)alc(3072ull * 1024 * 2);
  u16* w2t = (u16*)alc(1024ull * 3072 * 2);
  unsigned char* didx = (unsigned char*)alc(64ull * 128 * 128);

  hipFuncSetAttribute((const void*)gemm8<0>, hipFuncAttributeMaxDynamicSharedMemorySize, 131072);
  hipFuncSetAttribute((const void*)gemm8<1>, hipFuncAttributeMaxDynamicSharedMemorySize, 131072);
  hipFuncSetAttribute((const void*)gemm8<2>, hipFuncAttributeMaxDynamicSharedMemorySize, 131072);

  transpose_w<<<dim3(96, 32), dim3(32, 8), 0, stream>>>(Wqkv, wqkvt, 1024, 3072);
  transpose_w<<<dim3(32, 32), dim3(32, 8), 0, stream>>>(Wo, wot, 1024, 1024);
  transpose_w<<<dim3(96, 32), dim3(32, 8), 0, stream>>>(W1, w1t, 1024, 3072);
  transpose_w<<<dim3(32, 96), dim3(32, 8), 0, stream>>>(W2, w2t, 3072, 1024);
  embed_k<<<8192, 256, 0, stream>>>(z, hgs, atoms_emb, neigh_emb, xf, xb);
  didx_k<<<8192, 128, 0, stream>>>(pos, didx);

  for (int layer = 0; layer < 8; ++layer) {
    gemm8<0><<<384, 512, 131072, stream>>>(xb, wqkvt, bqkv, q, k, v, 3072, 1024);
    attn_kernel<<<1024, 256, 0, stream>>>(q, k, v, didx, dist_emb, big);
    gemm8<1><<<128, 512, 131072, stream>>>(big, wot, bo, proj, nullptr, nullptr, 1024, 1024);
    ln_res<<<2048, 256, 0, stream>>>(xf, proj, ln1g, ln1b, xb);
    gemm8<2><<<384, 512, 131072, stream>>>(xb, w1t, b1f, big, nullptr, nullptr, 3072, 1024);
    gemm8<1><<<128, 512, 131072, stream>>>(big, w2t, b2f, proj, nullptr, nullptr, 1024, 3072);
    ln_res<<<2048, 256, 0, stream>>>(xf, proj, ln2g, ln2b, xb);
  }
  extract_cls<<<64, 256, 0, stream>>>(xf, (float*)d_out);
}